// Round 8
// baseline (118.841 us; speedup 1.0000x reference)
//
#include <hip/hip_runtime.h>
#include <cstdint>
#include <cstddef>

#define N_NODES 50000
#define M_MOLS  512
#define DIMK    256
#define ODIM    256

// sampled-boundary parameters
#define NCH   99
#define CW    32
#define NSAMP (NCH * CW)      // 3168 sampled columns, monotone molid
#define NGAP  (NCH - 1)       // 98 inter-chunk gaps

#define NB_WPACK 32
#define K0_GRID  (NCH + NB_WPACK)        // 131
#define K1_GRID  (NGAP + NCH + 1)        // 198

#define NF4   (N_NODES / 4)   // 12500 float4 per out1 row
#define A_CAP 512             // max segment length (mean ~98, max ~140; 16 sigma safe)

typedef float  f32x4  __attribute__((ext_vector_type(4)));
typedef __bf16 bf16x8 __attribute__((ext_vector_type(8)));

static __device__ __forceinline__ short f2bf(float f) {
  unsigned u = __builtin_bit_cast(unsigned, f);
  u = u + 0x7fffu + ((u >> 16) & 1u);   // RNE to bf16
  return (short)(u >> 16);
}

static __device__ __forceinline__ int chunk_base(int c) {
  return (c < NCH - 1) ? c * 512 : (N_NODES - CW);   // 49968 for last
}

// ---------------- K0: sampled molid + W pack ----------------
__global__ __launch_bounds__(256) void k_prep(
    const float* __restrict__ mat, const float* __restrict__ W,
    int* __restrict__ smolid, int4* __restrict__ wp) {
  int b = blockIdx.x, t = threadIdx.x;
  if (b < NCH) {
    int base = chunk_base(b);
    int cp = (t & 15) * 2;      // column pair
    int rg = t >> 4;            // 16 row-groups of 32 rows
    int idx = -1, idy = -1;
    const float* p0 = mat + (size_t)(rg * 32) * N_NODES + base + cp;
#pragma unroll 16
    for (int r = 0; r < 32; r++) {
      float2 v = *(const float2*)(p0 + (size_t)r * N_NODES);
      if (v.x != 0.f) idx = rg * 32 + r;
      if (v.y != 0.f) idy = rg * 32 + r;
    }
    __shared__ int sm[16][32];
    sm[rg][cp] = idx; sm[rg][cp + 1] = idy;
    __syncthreads();
    if (t < 32) {
      int best = -1;
#pragma unroll
      for (int g = 0; g < 16; g++) best = max(best, sm[g][t]);
      smolid[b * CW + t] = best;
    }
  } else {
    // W pack into MFMA B-fragment layout (bf16)
    int g  = (b - NCH) * 256 + t;   // 0..8191
    int l  = g & 63;
    int Ju = g >> 6;
    int J  = Ju >> 3, u = Ju & 7;
    int j  = J * 16 + (l & 15);
    int k0 = u * 32 + (l >> 4) * 8;
    short sv[8];
#pragma unroll
    for (int i = 0; i < 8; i++) sv[i] = f2bf(W[(size_t)(k0 + i) * ODIM + j]);
    wp[Ju * 64 + l] = *(int4*)sv;
  }
}

// ---------------- K1: exact boundaries from samples -> strt[] ----------------
__global__ __launch_bounds__(256) void k_bnd(
    const float* __restrict__ mat, const int* __restrict__ smolid,
    int* __restrict__ strt) {
  int b = blockIdx.x, t = threadIdx.x;
  if (b < NGAP) {
    // gap between chunk b (last col p) and chunk b+1 (first col q)
    int p  = chunk_base(b) + CW - 1;
    int q  = chunk_base(b + 1);
    int ag = smolid[b * CW + CW - 1];   // molid(p)
    int bg = smolid[(b + 1) * CW];      // molid(q)
    if (bg == ag) return;
    int Wd = q - p;                     // columns p+1 .. q
    int nr = bg - ag;                   // rows ag+1 .. bg
    __shared__ int f1[512];
    int wave = t >> 6, l = t & 63;
    for (int rr = wave; rr < nr; rr += 4) {
      const float* rp = mat + (size_t)(ag + 1 + rr) * N_NODES + p + 1;
      int mn = 0x7fffffff;
      for (int i = l; i < Wd; i += 64)
        if (rp[i] != 0.f) { mn = i; break; }   // ascending -> first hit is min
#pragma unroll
      for (int o = 1; o < 64; o <<= 1) mn = min(mn, __shfl_xor(mn, o));
      if (l == 0) f1[rr] = mn;
    }
    __syncthreads();
    if (t == 0) {
      int run = 0x7fffffff;
      for (int rr = nr - 1; rr >= 0; rr--) {
        run = min(run, f1[rr]);
        strt[ag + 1 + rr] = p + 1 + run;
      }
    }
  } else if (b < NGAP + NCH) {
    // in-chunk transitions between adjacent sampled columns
    int cc = b - NGAP;
    if (t >= 1 && t < CW) {
      int prev = smolid[cc * CW + t - 1], cur = smolid[cc * CW + t];
      int col = chunk_base(cc) + t;
      for (int m = prev + 1; m <= cur; m++) strt[m] = col;
    }
  } else {
    // cleanup: head (m <= molid(0)) -> 0 ; tail (m > molid(N-1)) -> N
    int first = smolid[0], last = smolid[NSAMP - 1];
    for (int m = t; m <= M_MOLS; m += 256) {
      if (m <= first) strt[m] = 0;
      else if (m > last) strt[m] = N_NODES;
    }
  }
}

// ---------------- K2: monolith — one block per molecule ----------------
// zero row -> align GEMV -> softmax -> weight window -> fused MFMA pool
__global__ __launch_bounds__(512, 8) void k_main(
    const float* __restrict__ x, const float* __restrict__ wa,
    const float* __restrict__ ba, const int* __restrict__ strt,
    const int4* __restrict__ wp, const float* __restrict__ bias,
    float* __restrict__ out0, float* __restrict__ out1) {
  int m = blockIdx.x;
  int t = threadIdx.x;
  int seg_s = strt[m], seg_e = strt[m + 1];
  int L = seg_e - seg_s;

  __shared__ float a_lds[A_CAP];
  __shared__ __align__(16) short xs[16 * 256];
  __shared__ float fred[8];

  // ---- zero out1 row outside the weight window (stores don't stall)
  int s4 = seg_s >> 2, e4 = (seg_e + 3) >> 2;
  float4* orow = (float4*)out1 + (size_t)m * NF4;
  float4 z; z.x = z.y = z.z = z.w = 0.f;
  for (int q = t; q < s4; q += 512) orow[q] = z;
  for (int q = e4 + t; q < NF4; q += 512) orow[q] = z;

  // ---- align GEMV: a[i] = x[seg_s+i,:].wa + ba  (8 threads per row)
  float ba0 = ba[0];
  int sub = t & 7;
  float4 wv[8];
  {
    const float4* wr = (const float4*)wa + sub * 8;
#pragma unroll
    for (int i = 0; i < 8; i++) wv[i] = wr[i];
  }
  int nit = (L + 63) >> 6;
  for (int it = 0; it < nit; it++) {
    int ro  = it * 64 + (t >> 3);
    int row = seg_s + ro;
    float s = 0.f;
    if (row < seg_e) {
      const float4* xr = (const float4*)(x + (size_t)row * DIMK) + sub * 8;
#pragma unroll
      for (int i = 0; i < 8; i++) {
        float4 xv = xr[i];
        s += xv.x * wv[i].x + xv.y * wv[i].y + xv.z * wv[i].z + xv.w * wv[i].w;
      }
    }
    s += __shfl_xor(s, 1); s += __shfl_xor(s, 2); s += __shfl_xor(s, 4);
    if (sub == 0 && row < seg_e && ro < A_CAP) a_lds[ro] = s + ba0;
  }
  __syncthreads();

  // ---- softmax over a_lds[0..L)
  float mx = -3e38f;
  for (int i = t; i < L; i += 512) mx = fmaxf(mx, a_lds[i]);
#pragma unroll
  for (int o = 1; o < 64; o <<= 1) mx = fmaxf(mx, __shfl_xor(mx, o));
  if ((t & 63) == 0) fred[t >> 6] = mx;
  __syncthreads();
  mx = fred[0];
#pragma unroll
  for (int i = 1; i < 8; i++) mx = fmaxf(mx, fred[i]);
  __syncthreads();
  float sm = 0.f;
  for (int i = t; i < L; i += 512) sm += __expf(a_lds[i] - mx);
#pragma unroll
  for (int o = 1; o < 64; o <<= 1) sm += __shfl_xor(sm, o);
  if ((t & 63) == 0) fred[t >> 6] = sm;
  __syncthreads();
  sm = 0.f;
#pragma unroll
  for (int i = 0; i < 8; i++) sm += fred[i];
  float inv = (sm > 0.f) ? 1.f / sm : 0.f;
  for (int i = t; i < L; i += 512) a_lds[i] = __expf(a_lds[i] - mx) * inv;
  __syncthreads();

  // ---- weight window of out1 row
  for (int q = s4 + t; q < e4; q += 512) {
    int n = q * 4;
    float4 o;
    o.x = (n     >= seg_s && n     < seg_e) ? a_lds[n     - seg_s] : 0.f;
    o.y = (n + 1 >= seg_s && n + 1 < seg_e) ? a_lds[n + 1 - seg_s] : 0.f;
    o.z = (n + 2 >= seg_s && n + 2 < seg_e) ? a_lds[n + 2 - seg_s] : 0.f;
    o.w = (n + 3 >= seg_s && n + 3 < seg_e) ? a_lds[n + 3 - seg_s] : 0.f;
    orow[q] = o;
  }

  // ---- fused h-GEMM + pool (x re-read is L2/LLC-hot: same rows as align)
  int wv_id = t >> 6, l = t & 63;
  bf16x8 wfrag[2][8];
#pragma unroll
  for (int t2 = 0; t2 < 2; t2++)
#pragma unroll
    for (int u = 0; u < 8; u++)
      wfrag[t2][u] = __builtin_bit_cast(bf16x8, wp[((wv_id * 2 + t2) * 8 + u) * 64 + l]);
  float bias_r[2];
#pragma unroll
  for (int t2 = 0; t2 < 2; t2++) bias_r[t2] = bias[wv_id * 32 + t2 * 16 + (l & 15)];

  float pooled[2] = {0.f, 0.f};
  int r = l & 15, g = l >> 4;
  int swr = (r & 7) << 4;

  int srow = t >> 5;            // staging: 16 rows, 32 threads each
  int c0b  = (t & 31) * 16;     // byte col offset within row
  int ssw  = (srow & 7) << 4;
  char* lb = (char*)xs;

  int nt2 = (L + 15) >> 4;
  for (int tile = 0; tile < nt2; tile++) {
    int base = seg_s + tile * 16;
    __syncthreads();
    {
      int n = base + srow;
      short sv[8];
      if (n < seg_e) {
        const float4* src = (const float4*)(x + (size_t)n * DIMK) + (t & 31) * 2;
        float4 A = src[0], B = src[1];
        sv[0] = f2bf(A.x); sv[1] = f2bf(A.y); sv[2] = f2bf(A.z); sv[3] = f2bf(A.w);
        sv[4] = f2bf(B.x); sv[5] = f2bf(B.y); sv[6] = f2bf(B.z); sv[7] = f2bf(B.w);
      } else {
#pragma unroll
        for (int i = 0; i < 8; i++) sv[i] = 0;
      }
      *(int4*)(lb + (srow << 9) + (c0b ^ ssw)) = *(int4*)sv;
    }
    __syncthreads();
    bf16x8 af[8];
#pragma unroll
    for (int u = 0; u < 8; u++)
      af[u] = __builtin_bit_cast(bf16x8,
                *(const int4*)(lb + (r << 9) + (((u << 6) + (g << 4)) ^ swr)));
#pragma unroll
    for (int t2 = 0; t2 < 2; t2++) {
      f32x4 acc = {0.f, 0.f, 0.f, 0.f};
#pragma unroll
      for (int u = 0; u < 8; u++)
        acc = __builtin_amdgcn_mfma_f32_16x16x32_bf16(af[u], wfrag[t2][u], acc, 0, 0, 0);
      float p = 0.f;
#pragma unroll
      for (int i = 0; i < 4; i++) {
        int ridx = tile * 16 + (g << 2) + i;
        float wgt = (ridx < L) ? a_lds[ridx] : 0.f;
        float h = acc[i] + bias_r[t2];
        h = h > 0.f ? h : 0.01f * h;
        p += wgt * h;
      }
      pooled[t2] += p;
    }
  }
#pragma unroll
  for (int t2 = 0; t2 < 2; t2++) {
    float p = pooled[t2];
    p += __shfl_xor(p, 16);
    p += __shfl_xor(p, 32);
    pooled[t2] = p;
  }
  if (l < 16) {
#pragma unroll
    for (int t2 = 0; t2 < 2; t2++)
      out0[m * ODIM + wv_id * 32 + t2 * 16 + l] = pooled[t2];
  }
}

extern "C" void kernel_launch(void* const* d_in, const int* in_sizes, int n_in,
                              void* d_out, int out_size, void* d_ws, size_t ws_size,
                              hipStream_t stream) {
  const float* x   = (const float*)d_in[0];
  const float* mat = (const float*)d_in[1];
  // d_in[2] (mol_node_mask) redundant with mol_node_matrix — never read
  const float* W   = (const float*)d_in[3];
  const float* bA  = (const float*)d_in[4];
  const float* wa  = (const float*)d_in[5];
  const float* ba  = (const float*)d_in[6];

  float* out0 = (float*)d_out;
  float* out1 = out0 + (size_t)M_MOLS * ODIM;

  char* ws     = (char*)d_ws;
  int*  smolid = (int*) (ws);            // 3168 ints
  int*  strt   = (int*) (ws + 16384);    // 513 ints
  int4* wp     = (int4*)(ws + 20480);    // 128 KiB

  k_prep<<<K0_GRID, 256, 0, stream>>>(mat, W, smolid, wp);
  k_bnd <<<K1_GRID, 256, 0, stream>>>(mat, smolid, strt);
  k_main<<<M_MOLS, 512, 0, stream>>>(x, wa, ba, strt, wp, bA, out0, out1);
}

// Round 9
// 58.197 us; speedup vs baseline: 2.0420x; 2.0420x over previous
//
#include <hip/hip_runtime.h>
#include <cstdint>
#include <cstddef>

#define N_NODES 50000
#define M_MOLS  512
#define DIMK    256
#define ODIM    256

// sampled-boundary parameters
#define NCH   99
#define CW    32
#define NSAMP (NCH * CW)      // 3168 sampled columns, monotone molid
#define NGAP  (NCH - 1)       // 98 inter-chunk gaps

#define NB_WPACK 32
#define K0_GRID  (NCH + NB_WPACK)        // 131
#define K1_GRID  (NGAP + NCH + 1)        // 198

#define HG_ROWS 64
#define NB_HG   ((N_NODES + HG_ROWS - 1) / HG_ROWS)   // 782
#define NTILE   (N_NODES / 16)                         // 3125

#define POOL_BLOCKS 1024      // (m, j-half)
#define WPB   4               // writer blocks per out1 row
#define QPB   3125            // float4 per writer block
#define K4_GRID (POOL_BLOCKS + M_MOLS * WPB)          // 3072
#define NF4   (N_NODES / 4)   // 12500 float4 per out1 row
#define A_CAP 512             // max segment length (mean ~98, max ~140)

typedef float  f32x4  __attribute__((ext_vector_type(4)));
typedef __bf16 bf16x8 __attribute__((ext_vector_type(8)));

static __device__ __forceinline__ short f2bf(float f) {
  unsigned u = __builtin_bit_cast(unsigned, f);
  u = u + 0x7fffu + ((u >> 16) & 1u);   // RNE to bf16
  return (short)(u >> 16);
}
static __device__ __forceinline__ float bf2f(short s) {
  unsigned u = ((unsigned)(unsigned short)s) << 16;
  return __builtin_bit_cast(float, u);
}
static __device__ __forceinline__ float dot4(float4 a, float4 b) {
  return a.x * b.x + a.y * b.y + a.z * b.z + a.w * b.w;
}

static __device__ __forceinline__ int chunk_base(int c) {
  return (c < NCH - 1) ? c * 512 : (N_NODES - CW);   // 49968 for last
}

// ---------------- K0: sampled molid + W pack ----------------
__global__ __launch_bounds__(256) void k_prep(
    const float* __restrict__ mat, const float* __restrict__ W,
    int* __restrict__ smolid, int4* __restrict__ wp) {
  int b = blockIdx.x, t = threadIdx.x;
  if (b < NCH) {
    int base = chunk_base(b);
    int cp = (t & 15) * 2;      // column pair
    int rg = t >> 4;            // 16 row-groups of 32 rows
    int idx = -1, idy = -1;
    const float* p0 = mat + (size_t)(rg * 32) * N_NODES + base + cp;
#pragma unroll 16
    for (int r = 0; r < 32; r++) {
      float2 v = *(const float2*)(p0 + (size_t)r * N_NODES);
      if (v.x != 0.f) idx = rg * 32 + r;
      if (v.y != 0.f) idy = rg * 32 + r;
    }
    __shared__ int sm[16][32];
    sm[rg][cp] = idx; sm[rg][cp + 1] = idy;
    __syncthreads();
    if (t < 32) {
      int best = -1;
#pragma unroll
      for (int g = 0; g < 16; g++) best = max(best, sm[g][t]);
      smolid[b * CW + t] = best;
    }
  } else {
    // W pack into MFMA B-fragment layout (bf16)
    int g  = (b - NCH) * 256 + t;   // 0..8191
    int l  = g & 63;
    int Ju = g >> 6;
    int J  = Ju >> 3, u = Ju & 7;
    int j  = J * 16 + (l & 15);
    int k0 = u * 32 + (l >> 4) * 8;
    short sv[8];
#pragma unroll
    for (int i = 0; i < 8; i++) sv[i] = f2bf(W[(size_t)(k0 + i) * ODIM + j]);
    wp[Ju * 64 + l] = *(int4*)sv;
  }
}

// ---------------- K1: exact boundaries from samples -> strt[] ----------------
__global__ __launch_bounds__(256) void k_bnd(
    const float* __restrict__ mat, const int* __restrict__ smolid,
    int* __restrict__ strt) {
  int b = blockIdx.x, t = threadIdx.x;
  if (b < NGAP) {
    int p  = chunk_base(b) + CW - 1;
    int q  = chunk_base(b + 1);
    int ag = smolid[b * CW + CW - 1];
    int bg = smolid[(b + 1) * CW];
    if (bg == ag) return;
    int Wd = q - p;
    int nr = bg - ag;
    __shared__ int f1[512];
    int wave = t >> 6, l = t & 63;
    for (int rr = wave; rr < nr; rr += 4) {
      const float* rp = mat + (size_t)(ag + 1 + rr) * N_NODES + p + 1;
      int mn = 0x7fffffff;
      for (int i = l; i < Wd; i += 64)
        if (rp[i] != 0.f) { mn = i; break; }
#pragma unroll
      for (int o = 1; o < 64; o <<= 1) mn = min(mn, __shfl_xor(mn, o));
      if (l == 0) f1[rr] = mn;
    }
    __syncthreads();
    if (t == 0) {
      int run = 0x7fffffff;
      for (int rr = nr - 1; rr >= 0; rr--) {
        run = min(run, f1[rr]);
        strt[ag + 1 + rr] = p + 1 + run;
      }
    }
  } else if (b < NGAP + NCH) {
    int cc = b - NGAP;
    if (t >= 1 && t < CW) {
      int prev = smolid[cc * CW + t - 1], cur = smolid[cc * CW + t];
      int col = chunk_base(cc) + t;
      for (int m = prev + 1; m <= cur; m++) strt[m] = col;
    }
  } else {
    int first = smolid[0], last = smolid[NSAMP - 1];
    for (int m = t; m <= M_MOLS; m += 256) {
      if (m <= first) strt[m] = 0;
      else if (m > last) strt[m] = N_NODES;
    }
  }
}

// ---------------- K2: h-GEMM over all nodes + align GEMV ----------------
// hw layout (bf16): element (tile*256 + j)*16 + row, tile=n>>4, row=n&15.
// => per (tile,j): 32B holding 16 rows; K2 stores 8B/lane; K4 reads 2x int4.
__global__ __launch_bounds__(256) void k_hgemm(
    const float* __restrict__ x, const float* __restrict__ wa,
    const float* __restrict__ ba, const int4* __restrict__ wp,
    const float* __restrict__ bias, float* __restrict__ a,
    short* __restrict__ hw) {
  int b = blockIdx.x, t = threadIdx.x;
  int wave = t >> 6, l = t & 63;

  bf16x8 wfrag[4][8];
#pragma unroll
  for (int t2 = 0; t2 < 4; t2++)
#pragma unroll
    for (int u = 0; u < 8; u++)
      wfrag[t2][u] = __builtin_bit_cast(bf16x8, wp[((wave * 4 + t2) * 8 + u) * 64 + l]);
  float bias_r[4];
#pragma unroll
  for (int t2 = 0; t2 < 4; t2++) bias_r[t2] = bias[wave * 64 + t2 * 16 + (l & 15)];

  int srow = t >> 4, c0 = (t & 15) * 16;
  float4 wa_loc[4];
  {
    const float4* wr = (const float4*)wa + (c0 >> 2);
#pragma unroll
    for (int i = 0; i < 4; i++) wa_loc[i] = wr[i];
  }
  float ba0 = ba[0];

  __shared__ __align__(16) short xs[16 * 256];
  char* lb = (char*)xs;
  int r = l & 15, g = l >> 4, swr = (r & 7) << 4;
  int sw = (srow & 7) << 4;

  for (int tile = 0; tile < 4; ++tile) {
    int n0 = b * HG_ROWS + tile * 16;
    int n  = n0 + srow;
    __syncthreads();
    {
      short sv[16];
      float pa = 0.f;
      if (n < N_NODES) {
        const float4* src = (const float4*)(x + (size_t)n * DIMK + c0);
        float4 A = src[0], B = src[1], C = src[2], D = src[3];
        pa = dot4(A, wa_loc[0]) + dot4(B, wa_loc[1]) +
             dot4(C, wa_loc[2]) + dot4(D, wa_loc[3]);
        sv[0]  = f2bf(A.x); sv[1]  = f2bf(A.y); sv[2]  = f2bf(A.z); sv[3]  = f2bf(A.w);
        sv[4]  = f2bf(B.x); sv[5]  = f2bf(B.y); sv[6]  = f2bf(B.z); sv[7]  = f2bf(B.w);
        sv[8]  = f2bf(C.x); sv[9]  = f2bf(C.y); sv[10] = f2bf(C.z); sv[11] = f2bf(C.w);
        sv[12] = f2bf(D.x); sv[13] = f2bf(D.y); sv[14] = f2bf(D.z); sv[15] = f2bf(D.w);
      } else {
#pragma unroll
        for (int i = 0; i < 16; i++) sv[i] = 0;
      }
      *(int4*)(lb + (srow << 9) + (((c0 << 1)     ) ^ sw)) = *(int4*)(sv);
      *(int4*)(lb + (srow << 9) + (((c0 << 1) + 16) ^ sw)) = *(int4*)(sv + 8);
      // align reduce: 16 threads of a row are consecutive lanes
      pa += __shfl_xor(pa, 1); pa += __shfl_xor(pa, 2);
      pa += __shfl_xor(pa, 4); pa += __shfl_xor(pa, 8);
      if ((t & 15) == 0 && n < N_NODES) a[n] = pa + ba0;
    }
    __syncthreads();
    if (n0 >= N_NODES) continue;     // uniform per block
    bf16x8 af[8];
#pragma unroll
    for (int u = 0; u < 8; u++)
      af[u] = __builtin_bit_cast(bf16x8,
                *(const int4*)(lb + (r << 9) + (((u << 6) + (g << 4)) ^ swr)));
    int tadr = (n0 >> 4) * 256;
#pragma unroll
    for (int t2 = 0; t2 < 4; t2++) {
      f32x4 acc = {0.f, 0.f, 0.f, 0.f};
#pragma unroll
      for (int u = 0; u < 8; u++)
        acc = __builtin_amdgcn_mfma_f32_16x16x32_bf16(af[u], wfrag[t2][u], acc, 0, 0, 0);
      short hv[4];
#pragma unroll
      for (int i = 0; i < 4; i++) {
        float h = acc[i] + bias_r[t2];
        h = h > 0.f ? h : 0.01f * h;
        hv[i] = f2bf(h);
      }
      int j = wave * 64 + t2 * 16 + (l & 15);
      *(short4*)(hw + (size_t)(tadr + j) * 16 + g * 4) = *(short4*)hv;
    }
  }
}

// ---------------- K3: softmax stats -> wval[] ----------------
__global__ __launch_bounds__(256) void k_stats(
    const float* __restrict__ a, const int* __restrict__ strt,
    float* __restrict__ wval) {
  int m = blockIdx.x, t = threadIdx.x;
  int s = strt[m], e = strt[m + 1];

  float mx = -3e38f;
  for (int i = s + t; i < e; i += 256) mx = fmaxf(mx, a[i]);
#pragma unroll
  for (int o = 1; o < 64; o <<= 1) mx = fmaxf(mx, __shfl_xor(mx, o));
  __shared__ float r0[4];
  if ((t & 63) == 0) r0[t >> 6] = mx;
  __syncthreads();
  mx = fmaxf(fmaxf(r0[0], r0[1]), fmaxf(r0[2], r0[3]));

  float sm = 0.f;
  for (int i = s + t; i < e; i += 256) sm += __expf(a[i] - mx);
#pragma unroll
  for (int o = 1; o < 64; o <<= 1) sm += __shfl_xor(sm, o);
  __shared__ float r1[4];
  if ((t & 63) == 0) r1[t >> 6] = sm;
  __syncthreads();
  sm = r1[0] + r1[1] + r1[2] + r1[3];
  float inv = (sm > 0.f) ? 1.f / sm : 0.f;

  for (int i = s + t; i < e; i += 256) wval[i] = __expf(a[i] - mx) * inv;
}

// ---------------- K4: pool (weighted segment-sum of hw) + out1 writers ------
__global__ __launch_bounds__(256) void k_out(
    const short* __restrict__ hw, const float* __restrict__ wval,
    const int* __restrict__ strt, float* __restrict__ out0,
    float* __restrict__ out1) {
  int b = blockIdx.x, t = threadIdx.x;

  if (b < POOL_BLOCKS) {
    // ---- pool: m, j-half; sum over segment rows of wval[n]*h[n][j]
    int m = b >> 1, jh = b & 1;
    int s = strt[m], e = strt[m + 1];
    int L = e - s;
    __shared__ float wl[A_CAP];
    for (int i = t; i < L; i += 256) wl[i] = wval[s + i];
    __syncthreads();
    float acc = 0.f;
    if (L > 0) {
      int j = jh * 128 + (t & 127);
      int half = t >> 7;
      int t0 = s >> 4, t1 = (e - 1) >> 4;
      for (int tt = t0 + half; tt <= t1; tt += 2) {
        const int4* hp = (const int4*)(hw + (size_t)(tt * 256 + j) * 16);
        int4 lo = hp[0], hi = hp[1];
        int base = tt * 16 - s;
        const short* ls = (const short*)&lo;
        const short* hs = (const short*)&hi;
#pragma unroll
        for (int k = 0; k < 8; k++) {
          int rr = base + k;
          float wt = ((unsigned)rr < (unsigned)L) ? wl[rr] : 0.f;
          acc += wt * bf2f(ls[k]);
        }
#pragma unroll
        for (int k = 0; k < 8; k++) {
          int rr = base + 8 + k;
          float wt = ((unsigned)rr < (unsigned)L) ? wl[rr] : 0.f;
          acc += wt * bf2f(hs[k]);
        }
      }
    }
    __shared__ float pr[256];
    pr[t] = acc;
    __syncthreads();
    if (t < 128) out0[m * ODIM + jh * 128 + t] = pr[t] + pr[t + 128];
    return;
  }

  // ---- writer: quarter of an out1 row (zeros + weight window in one pass)
  int wb = b - POOL_BLOCKS;            // 0..2047
  int m = wb >> 2, quarter = wb & 3;
  int s = strt[m], e = strt[m + 1];
  const float4* wv4 = (const float4*)wval;
  float4* orow = (float4*)out1 + (size_t)m * NF4;
  int q0 = quarter * QPB, q1 = q0 + QPB;
  for (int q = q0 + t; q < q1; q += 256) {
    int n = q * 4;
    float4 w = wv4[q];
    float4 o;
    o.x = ((unsigned)(n     - s) < (unsigned)(e - s)) ? w.x : 0.f;
    o.y = ((unsigned)(n + 1 - s) < (unsigned)(e - s)) ? w.y : 0.f;
    o.z = ((unsigned)(n + 2 - s) < (unsigned)(e - s)) ? w.z : 0.f;
    o.w = ((unsigned)(n + 3 - s) < (unsigned)(e - s)) ? w.w : 0.f;
    orow[q] = o;
  }
}

extern "C" void kernel_launch(void* const* d_in, const int* in_sizes, int n_in,
                              void* d_out, int out_size, void* d_ws, size_t ws_size,
                              hipStream_t stream) {
  const float* x   = (const float*)d_in[0];
  const float* mat = (const float*)d_in[1];
  // d_in[2] (mol_node_mask) redundant with mol_node_matrix — never read
  const float* W   = (const float*)d_in[3];
  const float* bA  = (const float*)d_in[4];
  const float* wa  = (const float*)d_in[5];
  const float* ba  = (const float*)d_in[6];

  float* out0 = (float*)d_out;
  float* out1 = out0 + (size_t)M_MOLS * ODIM;

  char*  ws     = (char*)d_ws;
  float* a      = (float*)(ws);              // 50000 f
  int*   smolid = (int*)  (ws + 200064);     // 3168 i
  int*   strt   = (int*)  (ws + 212800);     // 513 i
  float* wval   = (float*)(ws + 214912);     // 50000 f
  int4*  wp     = (int4*) (ws + 414912);     // 128 KiB
  short* hw     = (short*)(ws + 557056);     // 25.6 MB packed bf16 h

  k_prep <<<K0_GRID, 256, 0, stream>>>(mat, W, smolid, wp);
  k_bnd  <<<K1_GRID, 256, 0, stream>>>(mat, smolid, strt);
  k_hgemm<<<NB_HG,   256, 0, stream>>>(x, wa, ba, wp, bA, a, hw);
  k_stats<<<M_MOLS,  256, 0, stream>>>(a, strt, wval);
  k_out  <<<K4_GRID, 256, 0, stream>>>(hw, wval, strt, out0, out1);
}